// Round 1
// baseline (455.650 us; speedup 1.0000x reference)
//
#include <hip/hip_runtime.h>

typedef __bf16 bf16_t;
typedef __bf16 bf16x8 __attribute__((ext_vector_type(8)));
typedef __bf16 bf16x4 __attribute__((ext_vector_type(4)));
typedef float  f32x4  __attribute__((ext_vector_type(4)));

#define MFMA16(A, B, C) __builtin_amdgcn_mfma_f32_16x16x32_bf16((A), (B), (C), 0, 0, 0)

// Problem constants
constexpr int BB = 4;
constexpr int SS = 2048;
constexpr int DD = 1024;     // model dim
constexpr int HH = 16;       // heads
constexpr int DH = 64;       // head dim
constexpr float SCALE = 0.125f;  // 1/sqrt(64)

// ---------------------------------------------------------------------------
// Kernel 1: transpose + convert weights: W[k][n] fp32 -> Wt[n][k] bf16
// grid (16,16,3), block 256
// ---------------------------------------------------------------------------
__global__ __launch_bounds__(256) void wtrans_kernel(
    const float* __restrict__ Wq, const float* __restrict__ Wk,
    const float* __restrict__ Wv, bf16_t* __restrict__ Wt)
{
    const float* W = blockIdx.z == 0 ? Wq : blockIdx.z == 1 ? Wk : Wv;
    bf16_t* T = Wt + ((size_t)blockIdx.z << 20);  // 1024*1024 per matrix

    __shared__ __align__(16) bf16_t tile[64][72];

    const int k0 = blockIdx.x * 64;
    const int n0 = blockIdx.y * 64;
    const int tid = threadIdx.x;

    // load 64(k) x 64(n) fp32 tile, store transposed bf16 into LDS
    #pragma unroll
    for (int i = 0; i < 4; i++) {
        int idx = tid + i * 256;           // 0..1023
        int kk = idx >> 4;                 // 0..63
        int nn = (idx & 15) * 4;           // 0..60
        f32x4 w = *(const f32x4*)&W[(size_t)(k0 + kk) * 1024 + n0 + nn];
        tile[nn + 0][kk] = (bf16_t)w[0];
        tile[nn + 1][kk] = (bf16_t)w[1];
        tile[nn + 2][kk] = (bf16_t)w[2];
        tile[nn + 3][kk] = (bf16_t)w[3];
    }
    __syncthreads();
    // write out rows of Wt (n-major, k contiguous)
    #pragma unroll
    for (int i = 0; i < 2; i++) {
        int idx = tid + i * 256;           // 0..511
        int nn = idx >> 3;                 // 0..63
        int kk = (idx & 7) * 8;            // 0..56
        *(bf16x8*)&T[(size_t)(n0 + nn) * 1024 + k0 + kk] =
            *(const bf16x8*)&tile[nn][kk];
    }
}

// ---------------------------------------------------------------------------
// Kernel 2: projection GEMM  C = A(fp32)[8192x1024] @ W -> bf16
//   which=0: qw[token][n]   which=1: kw[token][n]
//   which=2: vwt[b][h][d][s]  (pre-transposed for attention V staging)
// grid (8, 64, 3), block 256 (4 waves, each 64x64 of a 128x128 tile)
// ---------------------------------------------------------------------------
__global__ __launch_bounds__(256) void proj_kernel(
    const float* __restrict__ Aq, const float* __restrict__ Ak,
    const float* __restrict__ Av, const bf16_t* __restrict__ Wt,
    bf16_t* __restrict__ qw, bf16_t* __restrict__ kw, bf16_t* __restrict__ vwt)
{
    const int which = blockIdx.z;
    const float* A = which == 0 ? Aq : which == 1 ? Ak : Av;
    const bf16_t* T = Wt + ((size_t)which << 20);

    __shared__ __align__(16) bf16_t Alds[128][40];  // stride 80B = 5*16B, 2-way banks (free)

    const int tid = threadIdx.x;
    const int lane = tid & 63;
    const int wave = tid >> 6;
    const int quad = lane >> 4;
    const int l16 = lane & 15;

    const int m0 = blockIdx.y * 128;
    const int n0 = blockIdx.x * 128;
    const int wm = (wave >> 1) * 64;
    const int wn = (wave & 1) * 64;

    f32x4 zero4 = {0.f, 0.f, 0.f, 0.f};
    f32x4 acc[4][4];
    #pragma unroll
    for (int i = 0; i < 4; i++)
        #pragma unroll
        for (int j = 0; j < 4; j++) acc[i][j] = zero4;

    for (int k0 = 0; k0 < DD; k0 += 32) {
        // stage A tile: 128 rows x 32 k, fp32 -> bf16 LDS
        #pragma unroll
        for (int i = 0; i < 4; i++) {
            int idx = tid + i * 256;       // 0..1023
            int row = idx >> 3;            // 0..127
            int kc = (idx & 7) * 4;        // 0..28
            f32x4 a = *(const f32x4*)&A[(size_t)(m0 + row) * DD + k0 + kc];
            bf16x4 h;
            h[0] = (bf16_t)a[0]; h[1] = (bf16_t)a[1];
            h[2] = (bf16_t)a[2]; h[3] = (bf16_t)a[3];
            *(bf16x4*)&Alds[row][kc] = h;
        }
        __syncthreads();

        bf16x8 af[4], bfr[4];
        #pragma unroll
        for (int mi = 0; mi < 4; mi++)
            af[mi] = *(const bf16x8*)&Alds[wm + mi * 16 + l16][quad * 8];
        #pragma unroll
        for (int ni = 0; ni < 4; ni++)
            bfr[ni] = *(const bf16x8*)&T[(size_t)(n0 + wn + ni * 16 + l16) * 1024 + k0 + quad * 8];
        #pragma unroll
        for (int mi = 0; mi < 4; mi++)
            #pragma unroll
            for (int ni = 0; ni < 4; ni++)
                acc[mi][ni] = MFMA16(af[mi], bfr[ni], acc[mi][ni]);
        __syncthreads();
    }

    // epilogue: C/D layout col=lane&15, row=quad*4+reg
    if (which < 2) {
        bf16_t* Cout = which == 0 ? qw : kw;
        #pragma unroll
        for (int mi = 0; mi < 4; mi++)
            #pragma unroll
            for (int ni = 0; ni < 4; ni++)
                #pragma unroll
                for (int r = 0; r < 4; r++) {
                    int row = m0 + wm + mi * 16 + quad * 4 + r;
                    int col = n0 + wn + ni * 16 + l16;
                    Cout[(size_t)row * 1024 + col] = (bf16_t)acc[mi][ni][r];
                }
    } else {
        #pragma unroll
        for (int mi = 0; mi < 4; mi++)
            #pragma unroll
            for (int ni = 0; ni < 4; ni++)
                #pragma unroll
                for (int r = 0; r < 4; r++) {
                    int row = m0 + wm + mi * 16 + quad * 4 + r;  // b*S + s
                    int col = n0 + wn + ni * 16 + l16;           // h*64 + d
                    int b = row >> 11, s = row & 2047;
                    int h = col >> 6, d = col & 63;
                    vwt[(((size_t)((b * HH + h) * DH + d)) << 11) + s] =
                        (bf16_t)acc[mi][ni][r];
                }
    }
}

// ---------------------------------------------------------------------------
// Kernel 3: flash attention, transposed-score formulation.
//   S^T = K Q^T  (C row = key, col = query)  -> softmax state per lane-column
//   O^T = V^T P^T, epilogue writes out[b, q, h*64+d] fp32 (float4 stores)
// grid (16 q-tiles, 16 heads, 4 batch), block 256 (4 waves x 32 queries)
// ---------------------------------------------------------------------------
__global__ __launch_bounds__(256) void attn_kernel(
    const bf16_t* __restrict__ qw, const bf16_t* __restrict__ kw,
    const bf16_t* __restrict__ vwt, const float* __restrict__ v_mask,
    const float* __restrict__ q_mask, float* __restrict__ out)
{
    const int qt = blockIdx.x;
    const int h = blockIdx.y;
    const int b = blockIdx.z;

    __shared__ __align__(16) bf16_t Klds[128][72];    // [key][d]
    __shared__ __align__(16) bf16_t Vtlds[64][136];   // [d][key]
    __shared__ __align__(16) bf16_t Plds[4][32][152]; // per-wave [q][key]
    __shared__ __align__(16) float vml[128];

    const int tid = threadIdx.x;
    const int lane = tid & 63;
    const int wave = tid >> 6;
    const int quad = lane >> 4;
    const int l16 = lane & 15;

    const int q0 = qt * 128 + wave * 32;

    // Q fragments (B operand of S^T = K Q^T): bq[qi][dstep]
    bf16x8 bq[2][2];
    #pragma unroll
    for (int qi = 0; qi < 2; qi++)
        #pragma unroll
        for (int dk = 0; dk < 2; dk++) {
            int q = q0 + qi * 16 + l16;
            int d = dk * 32 + quad * 8;
            bq[qi][dk] = *(const bf16x8*)&qw[(size_t)(b * SS + q) * 1024 + h * 64 + d];
        }

    float m_i[2] = {-1e30f, -1e30f};
    float l_i[2] = {0.f, 0.f};
    f32x4 zero4 = {0.f, 0.f, 0.f, 0.f};
    f32x4 oacc[4][2];  // [d-tile][qi], row=d, col=q
    #pragma unroll
    for (int dt = 0; dt < 4; dt++) { oacc[dt][0] = zero4; oacc[dt][1] = zero4; }

    for (int kt = 0; kt < SS; kt += 128) {
        // stage K tile [128 keys][64 d]
        #pragma unroll
        for (int i = 0; i < 4; i++) {
            int idx = tid + i * 256;
            int row = idx >> 3;
            int dd = (idx & 7) * 8;
            *(bf16x8*)&Klds[row][dd] =
                *(const bf16x8*)&kw[(size_t)(b * SS + kt + row) * 1024 + h * 64 + dd];
        }
        // stage V^T tile [64 d][128 keys] (already transposed in global)
        #pragma unroll
        for (int i = 0; i < 4; i++) {
            int idx = tid + i * 256;
            int d = idx >> 4;
            int kk = (idx & 15) * 8;
            *(bf16x8*)&Vtlds[d][kk] =
                *(const bf16x8*)&vwt[(((size_t)((b * HH + h) * DH + d)) << 11) + kt + kk];
        }
        if (tid < 128) vml[tid] = (1.0f - v_mask[b * SS + kt + tid]) * 1e10f;
        __syncthreads();

        // S^T: 8 key-tiles x 2 q-tiles of 16x16
        f32x4 st[8][2];
        #pragma unroll
        for (int ki = 0; ki < 8; ki++) { st[ki][0] = zero4; st[ki][1] = zero4; }
        #pragma unroll
        for (int ki = 0; ki < 8; ki++) {
            bf16x8 ak0 = *(const bf16x8*)&Klds[ki * 16 + l16][quad * 8];
            bf16x8 ak1 = *(const bf16x8*)&Klds[ki * 16 + l16][32 + quad * 8];
            #pragma unroll
            for (int qi = 0; qi < 2; qi++) {
                st[ki][qi] = MFMA16(ak0, bq[qi][0], st[ki][qi]);
                st[ki][qi] = MFMA16(ak1, bq[qi][1], st[ki][qi]);
            }
        }
        // scale + additive key mask (row = key = ki*16 + quad*4 + r)
        #pragma unroll
        for (int ki = 0; ki < 8; ki++) {
            f32x4 vm4 = *(const f32x4*)&vml[ki * 16 + quad * 4];
            #pragma unroll
            for (int qi = 0; qi < 2; qi++)
                #pragma unroll
                for (int r = 0; r < 4; r++)
                    st[ki][qi][r] = st[ki][qi][r] * SCALE - vm4[r];
        }
        // online softmax along key dim (per lane-column q); quads hold disjoint keys
        #pragma unroll
        for (int qi = 0; qi < 2; qi++) {
            float mx = -1e30f;
            #pragma unroll
            for (int ki = 0; ki < 8; ki++)
                #pragma unroll
                for (int r = 0; r < 4; r++) mx = fmaxf(mx, st[ki][qi][r]);
            mx = fmaxf(mx, __shfl_xor(mx, 16));
            mx = fmaxf(mx, __shfl_xor(mx, 32));
            float m_new = fmaxf(m_i[qi], mx);
            float alpha = __expf(m_i[qi] - m_new);
            m_i[qi] = m_new;
            float rs = 0.f;
            #pragma unroll
            for (int ki = 0; ki < 8; ki++)
                #pragma unroll
                for (int r = 0; r < 4; r++) {
                    float p = __expf(st[ki][qi][r] - m_new);
                    st[ki][qi][r] = p;
                    rs += p;
                }
            rs += __shfl_xor(rs, 16);
            rs += __shfl_xor(rs, 32);
            l_i[qi] = l_i[qi] * alpha + rs;
            #pragma unroll
            for (int dt = 0; dt < 4; dt++) {
                oacc[dt][qi][0] *= alpha; oacc[dt][qi][1] *= alpha;
                oacc[dt][qi][2] *= alpha; oacc[dt][qi][3] *= alpha;
            }
        }
        // write P into wave-private LDS as [q][key] (b64, key-contiguous regs)
        #pragma unroll
        for (int qi = 0; qi < 2; qi++)
            #pragma unroll
            for (int ki = 0; ki < 8; ki++) {
                bf16x4 p4;
                p4[0] = (bf16_t)st[ki][qi][0]; p4[1] = (bf16_t)st[ki][qi][1];
                p4[2] = (bf16_t)st[ki][qi][2]; p4[3] = (bf16_t)st[ki][qi][3];
                *(bf16x4*)&Plds[wave][qi * 16 + l16][ki * 16 + quad * 4] = p4;
            }
        __syncthreads();  // conservative: ensures P visible before reads

        // O^T += V^T P^T : A-frag from Vtlds, B-frag from Plds
        #pragma unroll
        for (int ks = 0; ks < 4; ks++) {
            bf16x8 bp[2];
            #pragma unroll
            for (int qi = 0; qi < 2; qi++)
                bp[qi] = *(const bf16x8*)&Plds[wave][qi * 16 + l16][ks * 32 + quad * 8];
            #pragma unroll
            for (int dt = 0; dt < 4; dt++) {
                bf16x8 av = *(const bf16x8*)&Vtlds[dt * 16 + l16][ks * 32 + quad * 8];
                #pragma unroll
                for (int qi = 0; qi < 2; qi++)
                    oacc[dt][qi] = MFMA16(av, bp[qi], oacc[dt][qi]);
            }
        }
        __syncthreads();
    }

    // epilogue: out[b, q, h*64 + d] = oacc / l * q_mask, float4 along d
    #pragma unroll
    for (int qi = 0; qi < 2; qi++) {
        int q = q0 + qi * 16 + l16;
        float sc = q_mask[b * SS + q] / l_i[qi];
        #pragma unroll
        for (int dt = 0; dt < 4; dt++) {
            int d = dt * 16 + quad * 4;
            f32x4 o;
            o[0] = oacc[dt][qi][0] * sc; o[1] = oacc[dt][qi][1] * sc;
            o[2] = oacc[dt][qi][2] * sc; o[3] = oacc[dt][qi][3] * sc;
            *(f32x4*)&out[(size_t)(b * SS + q) * 1024 + h * 64 + d] = o;
        }
    }
}

// ---------------------------------------------------------------------------
extern "C" void kernel_launch(void* const* d_in, const int* in_sizes, int n_in,
                              void* d_out, int out_size, void* d_ws, size_t ws_size,
                              hipStream_t stream)
{
    const float* q  = (const float*)d_in[0];
    const float* k  = (const float*)d_in[1];
    const float* v  = (const float*)d_in[2];
    const float* vm = (const float*)d_in[3];
    const float* qm = (const float*)d_in[4];
    const float* Wq = (const float*)d_in[5];
    const float* Wk = (const float*)d_in[6];
    const float* Wv = (const float*)d_in[7];
    float* out = (float*)d_out;

    const size_t elems = (size_t)BB * SS * DD;  // 8388608
    bf16_t* qw  = (bf16_t*)d_ws;
    bf16_t* kw  = qw + elems;
    bf16_t* vwt = kw + elems;
    bf16_t* Wt  = vwt + elems;  // 3 x 1024 x 1024

    wtrans_kernel<<<dim3(16, 16, 3), 256, 0, stream>>>(Wq, Wk, Wv, Wt);
    proj_kernel<<<dim3(8, 64, 3), 256, 0, stream>>>(q, k, v, Wt, qw, kw, vwt);
    attn_kernel<<<dim3(16, 16, 4), 256, 0, stream>>>(qw, kw, vwt, vm, qm, out);
}

// Round 2
// 356.169 us; speedup vs baseline: 1.2793x; 1.2793x over previous
//
#include <hip/hip_runtime.h>

typedef __bf16 bf16_t;
typedef __bf16 bf16x8 __attribute__((ext_vector_type(8)));
typedef __bf16 bf16x4 __attribute__((ext_vector_type(4)));
typedef float  f32x4  __attribute__((ext_vector_type(4)));

#define MFMA16(A, B, C) __builtin_amdgcn_mfma_f32_16x16x32_bf16((A), (B), (C), 0, 0, 0)

constexpr int BB = 4;
constexpr int SS = 2048;
constexpr int DD = 1024;
constexpr int HH = 16;
constexpr int DH = 64;
constexpr float SCALE = 0.125f;

// async global->LDS, 16B per lane. LDS dest = wave-uniform base + lane*16.
__device__ __forceinline__ void async_copy16(const void* g, void* l) {
    __builtin_amdgcn_global_load_lds(
        (const __attribute__((address_space(1))) void*)g,
        (__attribute__((address_space(3))) void*)l, 16, 0, 0);
}

// ---------------------------------------------------------------------------
// fp32 -> bf16 conversion of q,k,v inputs. grid (4096,1,3), block 256.
// ---------------------------------------------------------------------------
__global__ __launch_bounds__(256) void conv_kernel(
    const float* __restrict__ q, const float* __restrict__ k,
    const float* __restrict__ v, bf16_t* __restrict__ outb)
{
    const float* src = blockIdx.z == 0 ? q : blockIdx.z == 1 ? k : v;
    bf16_t* dst = outb + ((size_t)blockIdx.z << 23);
    size_t i = ((size_t)blockIdx.x * 256 + threadIdx.x) * 8;
    f32x4 a = *(const f32x4*)&src[i];
    f32x4 b = *(const f32x4*)&src[i + 4];
    bf16x8 o;
    o[0] = (bf16_t)a[0]; o[1] = (bf16_t)a[1]; o[2] = (bf16_t)a[2]; o[3] = (bf16_t)a[3];
    o[4] = (bf16_t)b[0]; o[5] = (bf16_t)b[1]; o[6] = (bf16_t)b[2]; o[7] = (bf16_t)b[3];
    *(bf16x8*)&dst[i] = o;
}

// ---------------------------------------------------------------------------
// transpose + convert weights: W[k][n] fp32 -> Wt[n][k] bf16. grid (16,16,3).
// ---------------------------------------------------------------------------
__global__ __launch_bounds__(256) void wtrans_kernel(
    const float* __restrict__ Wq, const float* __restrict__ Wk,
    const float* __restrict__ Wv, bf16_t* __restrict__ Wt)
{
    const float* W = blockIdx.z == 0 ? Wq : blockIdx.z == 1 ? Wk : Wv;
    bf16_t* T = Wt + ((size_t)blockIdx.z << 20);

    __shared__ __align__(16) bf16_t tile[64][72];

    const int k0 = blockIdx.x * 64;
    const int n0 = blockIdx.y * 64;
    const int tid = threadIdx.x;

    #pragma unroll
    for (int i = 0; i < 4; i++) {
        int idx = tid + i * 256;
        int kk = idx >> 4;
        int nn = (idx & 15) * 4;
        f32x4 w = *(const f32x4*)&W[(size_t)(k0 + kk) * 1024 + n0 + nn];
        tile[nn + 0][kk] = (bf16_t)w[0];
        tile[nn + 1][kk] = (bf16_t)w[1];
        tile[nn + 2][kk] = (bf16_t)w[2];
        tile[nn + 3][kk] = (bf16_t)w[3];
    }
    __syncthreads();
    #pragma unroll
    for (int i = 0; i < 2; i++) {
        int idx = tid + i * 256;
        int nn = idx >> 3;
        int kk = (idx & 7) * 8;
        *(bf16x8*)&T[(size_t)(n0 + nn) * 1024 + k0 + kk] =
            *(const bf16x8*)&tile[nn][kk];
    }
}

// ---------------------------------------------------------------------------
// projection GEMM (m97 structure): C = Ab(bf16)[8192x1024] @ Wt^T -> bf16
// global_load_lds staging for A and B tiles, XOR chunk swizzle (16B chunks).
// grid (8, 64, 3), block 256: 4 waves, each 64x64 of the 128x128 tile.
// ---------------------------------------------------------------------------
__global__ __launch_bounds__(256) void proj_kernel(
    const bf16_t* __restrict__ Ab, const bf16_t* __restrict__ Wt,
    bf16_t* __restrict__ qw, bf16_t* __restrict__ kw, bf16_t* __restrict__ vwt)
{
    const int which = blockIdx.z;
    const bf16_t* A = Ab + ((size_t)which << 23);
    const bf16_t* T = Wt + ((size_t)which << 20);

    __shared__ bf16_t Alds[128 * 32];  // [row][32k], 16B chunk c stored at c^(row&3)
    __shared__ bf16_t Blds[128 * 32];

    const int tid = threadIdx.x;
    const int lane = tid & 63;
    const int wave = tid >> 6;
    const int quad = lane >> 4;
    const int l16 = lane & 15;

    const int m0 = blockIdx.y * 128;
    const int n0 = blockIdx.x * 128;
    const int wm = (wave >> 1) * 64;
    const int wn = (wave & 1) * 64;

    const int srow = lane >> 2;   // row within 16-row staging instr
    const int schk = lane & 3;    // physical 16B chunk

    f32x4 zero4 = {0.f, 0.f, 0.f, 0.f};
    f32x4 acc[4][4];
    #pragma unroll
    for (int i = 0; i < 4; i++)
        #pragma unroll
        for (int j = 0; j < 4; j++) acc[i][j] = zero4;

    for (int k0 = 0; k0 < DD; k0 += 32) {
        #pragma unroll
        for (int j = 0; j < 2; j++) {
            int r0 = wave * 32 + j * 16;
            int row = r0 + srow;
            int c = schk ^ (row & 3);
            async_copy16(&A[(size_t)(m0 + row) * 1024 + k0 + c * 8], &Alds[r0 * 32]);
            async_copy16(&T[(size_t)(n0 + row) * 1024 + k0 + c * 8], &Blds[r0 * 32]);
        }
        __syncthreads();

        const int sw = (quad ^ (l16 & 3)) << 3;
        bf16x8 af[4], bfr[4];
        #pragma unroll
        for (int mi = 0; mi < 4; mi++)
            af[mi] = *(const bf16x8*)&Alds[(wm + mi * 16 + l16) * 32 + sw];
        #pragma unroll
        for (int ni = 0; ni < 4; ni++)
            bfr[ni] = *(const bf16x8*)&Blds[(wn + ni * 16 + l16) * 32 + sw];
        #pragma unroll
        for (int mi = 0; mi < 4; mi++)
            #pragma unroll
            for (int ni = 0; ni < 4; ni++)
                acc[mi][ni] = MFMA16(af[mi], bfr[ni], acc[mi][ni]);
        __syncthreads();
    }

    // C/D layout: col=lane&15, row=quad*4+reg
    if (which < 2) {
        bf16_t* Cout = which == 0 ? qw : kw;
        #pragma unroll
        for (int mi = 0; mi < 4; mi++)
            #pragma unroll
            for (int ni = 0; ni < 4; ni++)
                #pragma unroll
                for (int r = 0; r < 4; r++) {
                    int row = m0 + wm + mi * 16 + quad * 4 + r;
                    int col = n0 + wn + ni * 16 + l16;
                    Cout[(size_t)row * 1024 + col] = (bf16_t)acc[mi][ni][r];
                }
    } else {
        // vwt[b][h][d][s]; the 4 acc regs are s-consecutive -> bf16x4 stores
        #pragma unroll
        for (int mi = 0; mi < 4; mi++)
            #pragma unroll
            for (int ni = 0; ni < 4; ni++) {
                int s0 = m0 + wm + mi * 16 + quad * 4;
                int col = n0 + wn + ni * 16 + l16;
                int b = s0 >> 11, s = s0 & 2047;
                int h = col >> 6, d = col & 63;
                bf16x4 p;
                p[0] = (bf16_t)acc[mi][ni][0]; p[1] = (bf16_t)acc[mi][ni][1];
                p[2] = (bf16_t)acc[mi][ni][2]; p[3] = (bf16_t)acc[mi][ni][3];
                *(bf16x4*)&vwt[(((size_t)((b * HH + h) * DH + d)) << 11) + s] = p;
            }
    }
}

// ---------------------------------------------------------------------------
// flash attention, transposed-score form. global_load_lds + XOR swizzle
// staging; P buffer wave-private (no extra barrier), split into 2 key-halves.
// grid (16 q-tiles, 16 heads, 4 batch), block 256 (4 waves x 32 queries).
// ---------------------------------------------------------------------------
__global__ __launch_bounds__(256) void attn_kernel(
    const bf16_t* __restrict__ qw, const bf16_t* __restrict__ kw,
    const bf16_t* __restrict__ vwt, const float* __restrict__ v_mask,
    const float* __restrict__ q_mask, float* __restrict__ out)
{
    const int qt = blockIdx.x;
    const int h = blockIdx.y;
    const int b = blockIdx.z;

    __shared__ bf16_t Klds[128 * 64];      // [key][d], chunk c at c^(key&7)
    __shared__ bf16_t Vtlds[64 * 128];     // [d][key], chunk c at c^(d&15)
    __shared__ bf16_t Plds[4][32 * 64];    // per-wave [q][64key], chunk c at c^(q&7)
    __shared__ float vml[128];

    const int tid = threadIdx.x;
    const int lane = tid & 63;
    const int wave = tid >> 6;
    const int quad = lane >> 4;
    const int l16 = lane & 15;

    const int q0 = qt * 128 + wave * 32;

    bf16x8 bq[2][2];
    #pragma unroll
    for (int qi = 0; qi < 2; qi++)
        #pragma unroll
        for (int dk = 0; dk < 2; dk++) {
            int q = q0 + qi * 16 + l16;
            int d = dk * 32 + quad * 8;
            bq[qi][dk] = *(const bf16x8*)&qw[(size_t)(b * SS + q) * 1024 + h * 64 + d];
        }

    float m_i[2] = {-1e30f, -1e30f};
    float l_i[2] = {0.f, 0.f};
    f32x4 zero4 = {0.f, 0.f, 0.f, 0.f};
    f32x4 oacc[4][2];
    #pragma unroll
    for (int dt = 0; dt < 4; dt++) { oacc[dt][0] = zero4; oacc[dt][1] = zero4; }

    const int kp = lane & 7, kro = lane >> 3;    // K staging: 8 rows/instr
    const int vp = lane & 15, vro = lane >> 4;   // V staging: 4 rows/instr

    for (int kt = 0; kt < SS; kt += 128) {
        #pragma unroll
        for (int j = 0; j < 4; j++) {
            int r0 = wave * 32 + j * 8;
            int row = r0 + kro;
            int c = kp ^ (row & 7);
            async_copy16(&kw[(size_t)(b * SS + kt + row) * 1024 + h * 64 + c * 8],
                         &Klds[r0 * 64]);
        }
        #pragma unroll
        for (int j = 0; j < 4; j++) {
            int r0 = wave * 16 + j * 4;
            int row = r0 + vro;
            int c = vp ^ (row & 15);
            async_copy16(&vwt[(((size_t)((b * HH + h) * DH + row)) << 11) + kt + c * 8],
                         &Vtlds[r0 * 128]);
        }
        if (tid < 128) vml[tid] = (1.0f - v_mask[b * SS + kt + tid]) * 1e10f;
        __syncthreads();

        // S^T = K Q^T
        f32x4 st[8][2];
        #pragma unroll
        for (int ki = 0; ki < 8; ki++) { st[ki][0] = zero4; st[ki][1] = zero4; }
        #pragma unroll
        for (int ki = 0; ki < 8; ki++) {
            int base = (ki * 16 + l16) * 64;
            bf16x8 ak0 = *(const bf16x8*)&Klds[base + ((quad ^ (l16 & 7)) << 3)];
            bf16x8 ak1 = *(const bf16x8*)&Klds[base + (((4 + quad) ^ (l16 & 7)) << 3)];
            #pragma unroll
            for (int qi = 0; qi < 2; qi++) {
                st[ki][qi] = MFMA16(ak0, bq[qi][0], st[ki][qi]);
                st[ki][qi] = MFMA16(ak1, bq[qi][1], st[ki][qi]);
            }
        }
        #pragma unroll
        for (int ki = 0; ki < 8; ki++) {
            f32x4 vm4 = *(const f32x4*)&vml[ki * 16 + quad * 4];
            #pragma unroll
            for (int qi = 0; qi < 2; qi++)
                #pragma unroll
                for (int r = 0; r < 4; r++)
                    st[ki][qi][r] = st[ki][qi][r] * SCALE - vm4[r];
        }
        // online softmax (key dim split over quads + 2 shuffles)
        #pragma unroll
        for (int qi = 0; qi < 2; qi++) {
            float mx = -1e30f;
            #pragma unroll
            for (int ki = 0; ki < 8; ki++)
                #pragma unroll
                for (int r = 0; r < 4; r++) mx = fmaxf(mx, st[ki][qi][r]);
            mx = fmaxf(mx, __shfl_xor(mx, 16));
            mx = fmaxf(mx, __shfl_xor(mx, 32));
            float m_new = fmaxf(m_i[qi], mx);
            float alpha = __expf(m_i[qi] - m_new);
            m_i[qi] = m_new;
            float rs = 0.f;
            #pragma unroll
            for (int ki = 0; ki < 8; ki++)
                #pragma unroll
                for (int r = 0; r < 4; r++) {
                    float p = __expf(st[ki][qi][r] - m_new);
                    st[ki][qi][r] = p;
                    rs += p;
                }
            rs += __shfl_xor(rs, 16);
            rs += __shfl_xor(rs, 32);
            l_i[qi] = l_i[qi] * alpha + rs;
            #pragma unroll
            for (int dt = 0; dt < 4; dt++) {
                oacc[dt][qi][0] *= alpha; oacc[dt][qi][1] *= alpha;
                oacc[dt][qi][2] *= alpha; oacc[dt][qi][3] *= alpha;
            }
        }
        // PV in two 64-key halves through wave-private P buffer
        #pragma unroll
        for (int half = 0; half < 2; half++) {
            #pragma unroll
            for (int qi = 0; qi < 2; qi++)
                #pragma unroll
                for (int kj = 0; kj < 4; kj++) {
                    int ki = half * 4 + kj;
                    bf16x4 p4;
                    p4[0] = (bf16_t)st[ki][qi][0]; p4[1] = (bf16_t)st[ki][qi][1];
                    p4[2] = (bf16_t)st[ki][qi][2]; p4[3] = (bf16_t)st[ki][qi][3];
                    int c = 2 * kj + (quad >> 1);
                    *(bf16x4*)&Plds[wave][(qi * 16 + l16) * 64 +
                                          ((c ^ (l16 & 7)) << 3) + (quad & 1) * 4] = p4;
                }
            asm volatile("" ::: "memory");  // order P writes before P reads (in-wave)
            #pragma unroll
            for (int ks = 0; ks < 2; ks++) {
                bf16x8 bp[2];
                #pragma unroll
                for (int qi = 0; qi < 2; qi++)
                    bp[qi] = *(const bf16x8*)&Plds[wave][(qi * 16 + l16) * 64 +
                                 (((ks * 4 + quad) ^ (l16 & 7)) << 3)];
                #pragma unroll
                for (int dt = 0; dt < 4; dt++) {
                    int rowv = dt * 16 + l16;
                    bf16x8 av = *(const bf16x8*)&Vtlds[rowv * 128 +
                                 ((((half * 2 + ks) * 4 + quad) ^ l16) << 3)];
                    #pragma unroll
                    for (int qi = 0; qi < 2; qi++)
                        oacc[dt][qi] = MFMA16(av, bp[qi], oacc[dt][qi]);
                }
            }
            asm volatile("" ::: "memory");  // order P reads before next half's writes
        }
        __syncthreads();
    }

    #pragma unroll
    for (int qi = 0; qi < 2; qi++) {
        int q = q0 + qi * 16 + l16;
        float sc = q_mask[b * SS + q] / l_i[qi];
        #pragma unroll
        for (int dt = 0; dt < 4; dt++) {
            int d = dt * 16 + quad * 4;
            f32x4 o;
            o[0] = oacc[dt][qi][0] * sc; o[1] = oacc[dt][qi][1] * sc;
            o[2] = oacc[dt][qi][2] * sc; o[3] = oacc[dt][qi][3] * sc;
            *(f32x4*)&out[(size_t)(b * SS + q) * 1024 + h * 64 + d] = o;
        }
    }
}

// ---------------------------------------------------------------------------
extern "C" void kernel_launch(void* const* d_in, const int* in_sizes, int n_in,
                              void* d_out, int out_size, void* d_ws, size_t ws_size,
                              hipStream_t stream)
{
    const float* q  = (const float*)d_in[0];
    const float* k  = (const float*)d_in[1];
    const float* v  = (const float*)d_in[2];
    const float* vm = (const float*)d_in[3];
    const float* qm = (const float*)d_in[4];
    const float* Wq = (const float*)d_in[5];
    const float* Wk = (const float*)d_in[6];
    const float* Wv = (const float*)d_in[7];
    float* out = (float*)d_out;

    const size_t elems = (size_t)BB * SS * DD;  // 8388608
    bf16_t* Ab  = (bf16_t*)d_ws;       // qb,kb,vb: 3*elems
    bf16_t* qw  = Ab + 3 * elems;
    bf16_t* kw  = qw + elems;
    bf16_t* vwt = kw + elems;
    bf16_t* Wt  = vwt + elems;         // 3 x 1024 x 1024

    conv_kernel<<<dim3(4096, 1, 3), 256, 0, stream>>>(q, k, v, Ab);
    wtrans_kernel<<<dim3(16, 16, 3), 256, 0, stream>>>(Wq, Wk, Wv, Wt);
    proj_kernel<<<dim3(8, 64, 3), 256, 0, stream>>>(Ab, Wt, qw, kw, vwt);
    attn_kernel<<<dim3(16, 16, 4), 256, 0, stream>>>(qw, kw, vwt, vm, qm, out);
}